// Round 1
// baseline (579.911 us; speedup 1.0000x reference)
//
#include <hip/hip_runtime.h>
#include <hip/hip_bf16.h>
#include <math.h>

#define C_CURV 0.01f
#define SQRT_C 0.1f
#define EPSF   1e-15f
#define MAX_TANH 0.99999f   // 1 - 1e-5

__device__ __forceinline__ float wave_reduce_sum(float v) {
    #pragma unroll
    for (int off = 32; off > 0; off >>= 1)
        v += __shfl_xor(v, off, 64);
    return v;
}

// One 64-thread wave per triplet. Each lane owns dims d and d+64.
__global__ __launch_bounds__(64)
void build_queries(const float* __restrict__ ent,
                   const int*   __restrict__ trip,
                   const float* __restrict__ rel_diag,
                   const float* __restrict__ rel_trans,
                   const float* __restrict__ ent_bias,
                   float* __restrict__ q_out,    // [B][128]
                   float* __restrict__ q2_out,   // [B]
                   float* __restrict__ bs_out)   // [B]
{
    const int b = blockIdx.x;
    const int d = threadIdx.x;            // 0..63
    const int s = trip[3 * b + 0];
    const int r = trip[3 * b + 1];

    const float* srow = ent + (size_t)s * 128;
    float x0 = srow[d], x1 = srow[d + 64];

    // log_map_zero(s_emb)
    float n1 = fmaxf(sqrtf(wave_reduce_sum(x0 * x0 + x1 * x1)), EPSF);
    float a1 = atanhf(fminf(SQRT_C * n1, MAX_TANH)) / (SQRT_C * n1);
    float u0 = a1 * x0, u1 = a1 * x1;

    // rot * u, then exp_map_zero
    const float* rrow = rel_diag + (size_t)r * 128;
    float v0 = rrow[d] * u0, v1 = rrow[d + 64] * u1;
    float n2 = fmaxf(sqrtf(wave_reduce_sum(v0 * v0 + v1 * v1)), EPSF);
    float s2 = tanhf(SQRT_C * n2) / (SQRT_C * n2);
    float rs0 = s2 * v0, rs1 = s2 * v1;

    // exp_map_zero(rel_trans)
    const float* trow = rel_trans + (size_t)r * 128;
    float t0 = trow[d], t1 = trow[d + 64];
    float n3 = fmaxf(sqrtf(wave_reduce_sum(t0 * t0 + t1 * t1)), EPSF);
    float s3 = tanhf(SQRT_C * n3) / (SQRT_C * n3);
    float tr0 = s3 * t0, tr1 = s3 * t1;

    // mobius_add(rot_s, t_r)
    float x2 = wave_reduce_sum(rs0 * rs0 + rs1 * rs1);
    float y2 = wave_reduce_sum(tr0 * tr0 + tr1 * tr1);
    float xy = wave_reduce_sum(rs0 * tr0 + rs1 * tr1);
    float cA = 1.f + 2.f * C_CURV * xy + C_CURV * y2;
    float cB = 1.f - C_CURV * x2;
    float den = 1.f + 2.f * C_CURV * xy + C_CURV * C_CURV * x2 * y2;
    den = fmaxf(den, EPSF);
    float inv = 1.f / den;
    float q0 = (cA * rs0 + cB * tr0) * inv;
    float q1 = (cA * rs1 + cB * tr1) * inv;

    float q2 = wave_reduce_sum(q0 * q0 + q1 * q1);

    q_out[(size_t)b * 128 + d]      = q0;
    q_out[(size_t)b * 128 + d + 64] = q1;
    if (d == 0) { q2_out[b] = q2; bs_out[b] = ent_bias[s]; }
}

// One entity per thread; entity row register-resident; loop over all queries.
__global__ __launch_bounds__(64)
void score_kernel(const float* __restrict__ ent,
                  const float* __restrict__ ent_bias,
                  const float* __restrict__ qv,   // [B][128]
                  const float* __restrict__ q2a,  // [B]
                  const float* __restrict__ bsa,  // [B]
                  float* __restrict__ out,        // [B][E]
                  int E, int B)
{
    const int e = blockIdx.x * 64 + threadIdx.x;
    const bool valid = (e < E);
    const int el = valid ? e : 0;

    float er[128];
    float e2 = 0.f;
    const float4* rp = (const float4*)(ent + (size_t)el * 128);
    #pragma unroll
    for (int i = 0; i < 32; ++i) {
        float4 v = rp[i];
        er[4 * i + 0] = v.x; er[4 * i + 1] = v.y;
        er[4 * i + 2] = v.z; er[4 * i + 3] = v.w;
        e2 += v.x * v.x + v.y * v.y + v.z * v.z + v.w * v.w;
    }
    const float be = ent_bias[el];
    const float c = C_CURV;

    for (int b = 0; b < B; ++b) {
        const float4* q4 = (const float4*)(qv + (size_t)b * 128);
        float a0 = 0.f, a1 = 0.f, a2 = 0.f, a3 = 0.f;
        #pragma unroll
        for (int i = 0; i < 32; ++i) {
            float4 qq = q4[i];
            a0 = fmaf(er[4 * i + 0], qq.x, a0);
            a1 = fmaf(er[4 * i + 1], qq.y, a1);
            a2 = fmaf(er[4 * i + 2], qq.z, a2);
            a3 = fmaf(er[4 * i + 3], qq.w, a3);
        }
        float dot = (a0 + a1) + (a2 + a3);

        float q2 = q2a[b];
        float bs = bsa[b];
        float T  = fmaf(-2.f * c, dot, 1.f);
        float A  = fmaf(c, e2, T);
        float Bq = fmaf(-c, q2, 1.f);
        float den = fmaf(c * c * q2, e2, T);
        den = fmaxf(den, EPSF);
        float inv = __builtin_amdgcn_rcpf(den);
        float num2 = A * A * q2 + Bq * Bq * e2 - 2.f * A * Bq * dot;
        float score = fmaf(-num2 * inv, inv, be + bs);
        if (valid) out[(size_t)b * (size_t)E + e] = score;
    }
}

extern "C" void kernel_launch(void* const* d_in, const int* in_sizes, int n_in,
                              void* d_out, int out_size, void* d_ws, size_t ws_size,
                              hipStream_t stream) {
    const float* ent       = (const float*)d_in[0];
    // d_in[1] = rel_embedding (unused)
    const int*   trip      = (const int*)d_in[2];
    const float* rel_diag  = (const float*)d_in[3];
    const float* rel_trans = (const float*)d_in[4];
    const float* ent_bias  = (const float*)d_in[5];

    const int D = 128;
    const int E = in_sizes[0] / D;
    const int B = in_sizes[2] / 3;

    float* wsf   = (float*)d_ws;
    float* q_ws  = wsf;                      // B*128
    float* q2_ws = wsf + (size_t)B * 128;    // B
    float* bs_ws = q2_ws + B;                // B

    build_queries<<<B, 64, 0, stream>>>(ent, trip, rel_diag, rel_trans, ent_bias,
                                        q_ws, q2_ws, bs_ws);

    const int nblk = (E + 63) / 64;
    score_kernel<<<nblk, 64, 0, stream>>>(ent, ent_bias, q_ws, q2_ws, bs_ws,
                                          (float*)d_out, E, B);
}

// Round 2
// 485.239 us; speedup vs baseline: 1.1951x; 1.1951x over previous
//
#include <hip/hip_runtime.h>
#include <hip/hip_bf16.h>
#include <math.h>

#define C_CURV 0.01f
#define SQRT_C 0.1f
#define EPSF   1e-15f
#define MAX_TANH 0.99999f   // 1 - 1e-5

__device__ __forceinline__ float wave_reduce_sum(float v) {
    #pragma unroll
    for (int off = 32; off > 0; off >>= 1)
        v += __shfl_xor(v, off, 64);
    return v;
}

// One 64-thread wave per triplet. Each lane owns dims d and d+64.
__global__ __launch_bounds__(64)
void build_queries(const float* __restrict__ ent,
                   const int*   __restrict__ trip,
                   const float* __restrict__ rel_diag,
                   const float* __restrict__ rel_trans,
                   const float* __restrict__ ent_bias,
                   float* __restrict__ q_out,    // [B][128]
                   float* __restrict__ q2_out,   // [B]
                   float* __restrict__ bs_out)   // [B]
{
    const int b = blockIdx.x;
    const int d = threadIdx.x;            // 0..63
    const int s = trip[3 * b + 0];
    const int r = trip[3 * b + 1];

    const float* srow = ent + (size_t)s * 128;
    float x0 = srow[d], x1 = srow[d + 64];

    // log_map_zero(s_emb)
    float n1 = fmaxf(sqrtf(wave_reduce_sum(x0 * x0 + x1 * x1)), EPSF);
    float a1 = atanhf(fminf(SQRT_C * n1, MAX_TANH)) / (SQRT_C * n1);
    float u0 = a1 * x0, u1 = a1 * x1;

    // rot * u, then exp_map_zero
    const float* rrow = rel_diag + (size_t)r * 128;
    float v0 = rrow[d] * u0, v1 = rrow[d + 64] * u1;
    float n2 = fmaxf(sqrtf(wave_reduce_sum(v0 * v0 + v1 * v1)), EPSF);
    float s2 = tanhf(SQRT_C * n2) / (SQRT_C * n2);
    float rs0 = s2 * v0, rs1 = s2 * v1;

    // exp_map_zero(rel_trans)
    const float* trow = rel_trans + (size_t)r * 128;
    float t0 = trow[d], t1 = trow[d + 64];
    float n3 = fmaxf(sqrtf(wave_reduce_sum(t0 * t0 + t1 * t1)), EPSF);
    float s3 = tanhf(SQRT_C * n3) / (SQRT_C * n3);
    float tr0 = s3 * t0, tr1 = s3 * t1;

    // mobius_add(rot_s, t_r)
    float x2 = wave_reduce_sum(rs0 * rs0 + rs1 * rs1);
    float y2 = wave_reduce_sum(tr0 * tr0 + tr1 * tr1);
    float xy = wave_reduce_sum(rs0 * tr0 + rs1 * tr1);
    float cA = 1.f + 2.f * C_CURV * xy + C_CURV * y2;
    float cB = 1.f - C_CURV * x2;
    float den = 1.f + 2.f * C_CURV * xy + C_CURV * C_CURV * x2 * y2;
    den = fmaxf(den, EPSF);
    float inv = 1.f / den;
    float q0 = (cA * rs0 + cB * tr0) * inv;
    float q1 = (cA * rs1 + cB * tr1) * inv;

    float q2 = wave_reduce_sum(q0 * q0 + q1 * q1);

    q_out[(size_t)b * 128 + d]      = q0;
    q_out[(size_t)b * 128 + d + 64] = q1;
    if (d == 0) { q2_out[b] = q2; bs_out[b] = ent_bias[s]; }
}

// One entity per thread, entity row in 32 NAMED float4 registers (no alloca →
// no scratch demotion). gridDim.y splits the B queries into chunks of 64 for
// wave-count. 256-thread blocks.
__global__ __launch_bounds__(256, 2)
void score_kernel(const float* __restrict__ ent,
                  const float* __restrict__ ent_bias,
                  const float* __restrict__ qv,   // [B][128]
                  const float* __restrict__ q2a,  // [B]
                  const float* __restrict__ bsa,  // [B]
                  float* __restrict__ out,        // [B][E]
                  int E, int B)
{
    const int e = blockIdx.x * 256 + threadIdx.x;
    const bool valid = (e < E);
    const int el = valid ? e : 0;
    const int b0 = blockIdx.y * 64;

    const float4* rp = (const float4*)(ent + (size_t)el * 128);
    float e2 = 0.f;

#define ELOAD(i) float4 E##i = rp[i]; \
    e2 = fmaf(E##i.x, E##i.x, fmaf(E##i.y, E##i.y, fmaf(E##i.z, E##i.z, fmaf(E##i.w, E##i.w, e2))));
    ELOAD(0)  ELOAD(1)  ELOAD(2)  ELOAD(3)  ELOAD(4)  ELOAD(5)  ELOAD(6)  ELOAD(7)
    ELOAD(8)  ELOAD(9)  ELOAD(10) ELOAD(11) ELOAD(12) ELOAD(13) ELOAD(14) ELOAD(15)
    ELOAD(16) ELOAD(17) ELOAD(18) ELOAD(19) ELOAD(20) ELOAD(21) ELOAD(22) ELOAD(23)
    ELOAD(24) ELOAD(25) ELOAD(26) ELOAD(27) ELOAD(28) ELOAD(29) ELOAD(30) ELOAD(31)
#undef ELOAD

    const float be = ent_bias[el];
    const float c = C_CURV;

    #pragma unroll 1
    for (int bb = 0; bb < 64; ++bb) {
        const int b = b0 + bb;
        if (b >= B) break;
        const float4* q4 = (const float4*)(qv + (size_t)b * 128);
        float a0 = 0.f, a1 = 0.f, a2 = 0.f, a3 = 0.f;

#define STEP(i) { float4 qq = q4[i]; \
        a0 = fmaf(E##i.x, qq.x, a0); a1 = fmaf(E##i.y, qq.y, a1); \
        a2 = fmaf(E##i.z, qq.z, a2); a3 = fmaf(E##i.w, qq.w, a3); }
        STEP(0)  STEP(1)  STEP(2)  STEP(3)  STEP(4)  STEP(5)  STEP(6)  STEP(7)
        STEP(8)  STEP(9)  STEP(10) STEP(11) STEP(12) STEP(13) STEP(14) STEP(15)
        STEP(16) STEP(17) STEP(18) STEP(19) STEP(20) STEP(21) STEP(22) STEP(23)
        STEP(24) STEP(25) STEP(26) STEP(27) STEP(28) STEP(29) STEP(30) STEP(31)
#undef STEP
        float dot = (a0 + a1) + (a2 + a3);

        float q2 = q2a[b];
        float bs = bsa[b];
        float T  = fmaf(-2.f * c, dot, 1.f);
        float A  = fmaf(c, e2, T);
        float Bq = fmaf(-c, q2, 1.f);
        float den = fmaf(c * c * q2, e2, T);
        den = fmaxf(den, EPSF);
        float inv = __builtin_amdgcn_rcpf(den);
        float num2 = A * A * q2 + Bq * Bq * e2 - 2.f * A * Bq * dot;
        float score = fmaf(-num2 * inv, inv, be + bs);
        if (valid) __builtin_nontemporal_store(score, &out[(size_t)b * (size_t)E + e]);
    }
}

extern "C" void kernel_launch(void* const* d_in, const int* in_sizes, int n_in,
                              void* d_out, int out_size, void* d_ws, size_t ws_size,
                              hipStream_t stream) {
    const float* ent       = (const float*)d_in[0];
    // d_in[1] = rel_embedding (unused)
    const int*   trip      = (const int*)d_in[2];
    const float* rel_diag  = (const float*)d_in[3];
    const float* rel_trans = (const float*)d_in[4];
    const float* ent_bias  = (const float*)d_in[5];

    const int D = 128;
    const int E = in_sizes[0] / D;
    const int B = in_sizes[2] / 3;

    float* wsf   = (float*)d_ws;
    float* q_ws  = wsf;                      // B*128
    float* q2_ws = wsf + (size_t)B * 128;    // B
    float* bs_ws = q2_ws + B;                // B

    build_queries<<<B, 64, 0, stream>>>(ent, trip, rel_diag, rel_trans, ent_bias,
                                        q_ws, q2_ws, bs_ws);

    dim3 grid((E + 255) / 256, (B + 63) / 64);
    score_kernel<<<grid, 256, 0, stream>>>(ent, ent_bias, q_ws, q2_ws, bs_ws,
                                           (float*)d_out, E, B);
}

// Round 3
// 147.632 us; speedup vs baseline: 3.9281x; 3.2868x over previous
//
#include <hip/hip_runtime.h>
#include <hip/hip_bf16.h>
#include <math.h>

typedef short short8 __attribute__((ext_vector_type(8)));
typedef float f32x4  __attribute__((ext_vector_type(4)));

#define C_CURV 0.01f
#define SQRT_C 0.1f
#define EPSF   1e-15f
#define MAX_TANH 0.99999f   // 1 - 1e-5

__device__ __forceinline__ unsigned short f32_to_bf16(float x) {
    unsigned u = __builtin_bit_cast(unsigned, x);
    u += 0x7FFFu + ((u >> 16) & 1u);          // RNE
    return (unsigned short)(u >> 16);
}
__device__ __forceinline__ float bf16_to_f32(unsigned short h) {
    unsigned u = ((unsigned)h) << 16;
    return __builtin_bit_cast(float, u);
}

__device__ __forceinline__ float wave_reduce_sum(float v) {
    #pragma unroll
    for (int off = 32; off > 0; off >>= 1)
        v += __shfl_xor(v, off, 64);
    return v;
}

// One 64-thread wave per triplet. Lane owns dims d and d+64.
// Emits bf16 hi/lo split of query + q2 + subject bias.
__global__ __launch_bounds__(64)
void build_queries(const float* __restrict__ ent,
                   const int*   __restrict__ trip,
                   const float* __restrict__ rel_diag,
                   const float* __restrict__ rel_trans,
                   const float* __restrict__ ent_bias,
                   unsigned short* __restrict__ qh,   // [B][128] bf16 hi
                   unsigned short* __restrict__ qlo,  // [B][128] bf16 lo
                   float* __restrict__ q2_out,        // [B]
                   float* __restrict__ bs_out)        // [B]
{
    const int b = blockIdx.x;
    const int d = threadIdx.x;
    const int s = trip[3 * b + 0];
    const int r = trip[3 * b + 1];

    const float* srow = ent + (size_t)s * 128;
    float x0 = srow[d], x1 = srow[d + 64];

    float n1 = fmaxf(sqrtf(wave_reduce_sum(x0 * x0 + x1 * x1)), EPSF);
    float a1 = atanhf(fminf(SQRT_C * n1, MAX_TANH)) / (SQRT_C * n1);
    float u0 = a1 * x0, u1 = a1 * x1;

    const float* rrow = rel_diag + (size_t)r * 128;
    float v0 = rrow[d] * u0, v1 = rrow[d + 64] * u1;
    float n2 = fmaxf(sqrtf(wave_reduce_sum(v0 * v0 + v1 * v1)), EPSF);
    float s2 = tanhf(SQRT_C * n2) / (SQRT_C * n2);
    float rs0 = s2 * v0, rs1 = s2 * v1;

    const float* trow = rel_trans + (size_t)r * 128;
    float t0 = trow[d], t1 = trow[d + 64];
    float n3 = fmaxf(sqrtf(wave_reduce_sum(t0 * t0 + t1 * t1)), EPSF);
    float s3 = tanhf(SQRT_C * n3) / (SQRT_C * n3);
    float tr0 = s3 * t0, tr1 = s3 * t1;

    float x2 = wave_reduce_sum(rs0 * rs0 + rs1 * rs1);
    float y2 = wave_reduce_sum(tr0 * tr0 + tr1 * tr1);
    float xy = wave_reduce_sum(rs0 * tr0 + rs1 * tr1);
    float cA = 1.f + 2.f * C_CURV * xy + C_CURV * y2;
    float cB = 1.f - C_CURV * x2;
    float den = 1.f + 2.f * C_CURV * xy + C_CURV * C_CURV * x2 * y2;
    den = fmaxf(den, EPSF);
    float inv = 1.f / den;
    float q0 = (cA * rs0 + cB * tr0) * inv;
    float q1 = (cA * rs1 + cB * tr1) * inv;

    float q2 = wave_reduce_sum(q0 * q0 + q1 * q1);

    unsigned short h0 = f32_to_bf16(q0);
    unsigned short h1 = f32_to_bf16(q1);
    qh [(size_t)b * 128 + d]      = h0;
    qh [(size_t)b * 128 + d + 64] = h1;
    qlo[(size_t)b * 128 + d]      = f32_to_bf16(q0 - bf16_to_f32(h0));
    qlo[(size_t)b * 128 + d + 64] = f32_to_bf16(q1 - bf16_to_f32(h1));
    if (d == 0) { q2_out[b] = q2; bs_out[b] = ent_bias[s]; }
}

// Tile: 128 queries (bm) x 128 entities (bn), 4 waves of 64x64, K=128 resident.
// Entities: fp32 -> bf16 hi/lo converted into XOR-swizzled LDS. Queries: bf16
// hi/lo fragments read directly from global (L2-hot, 256 KB total).
// dot = qh*eh + qh*el + ql*eh (fp32 MFMA accumulate), fused rational epilogue.
__global__ __launch_bounds__(256, 2)
void gemm_score(const float* __restrict__ ent,
                const float* __restrict__ ent_bias,
                const unsigned short* __restrict__ qh,
                const unsigned short* __restrict__ ql,
                const float* __restrict__ q2a,
                const float* __restrict__ bsa,
                float* __restrict__ out,
                int E, int B)
{
    extern __shared__ char smem[];
    char*  EH  = smem;                        // 32768: ent hi bf16 [128][128]
    char*  EL  = smem + 32768;                // 32768: ent lo bf16
    float* E2L = (float*)(smem + 65536);      // 128
    float* EBL = (float*)(smem + 66048);      // 128
    float* Q2L = (float*)(smem + 66560);      // 128
    float* BSL = (float*)(smem + 67072);      // 128
    float* P2  = (float*)(smem + 67584);      // 256  (total 68608 B)

    const int t  = threadIdx.x;
    const int bn = blockIdx.x, bm = blockIdx.y;

    // ---- stage entity tile (convert + swizzle + e2 partials) ----
    {
        const int r = t >> 1, h = t & 1;
        int g = bn * 128 + r; if (g > E - 1) g = E - 1;
        const float4* src = (const float4*)(ent + (size_t)g * 128 + h * 64);
        const int swzr = (r & 7) << 4;
        float ss = 0.f;
        #pragma unroll
        for (int j = 0; j < 8; ++j) {
            float4 v0 = src[2 * j], v1 = src[2 * j + 1];
            float xv[8] = {v0.x, v0.y, v0.z, v0.w, v1.x, v1.y, v1.z, v1.w};
            short8 hi8, lo8;
            #pragma unroll
            for (int q = 0; q < 8; ++q) {
                float x = xv[q];
                unsigned short hb = f32_to_bf16(x);
                hi8[q] = (short)hb;
                lo8[q] = (short)f32_to_bf16(x - bf16_to_f32(hb));
                ss = fmaf(x, x, ss);
            }
            const int bo = (h * 128 + j * 16) ^ swzr;
            *(short8*)(EH + r * 256 + bo) = hi8;
            *(short8*)(EL + r * 256 + bo) = lo8;
        }
        P2[t] = ss;
        if (t < 128) {
            int gc = bn * 128 + t; if (gc > E - 1) gc = E - 1;
            EBL[t] = ent_bias[gc];
            int gr = bm * 128 + t; if (gr > B - 1) gr = B - 1;
            Q2L[t] = q2a[gr];
            BSL[t] = bsa[gr];
        }
    }
    __syncthreads();
    if (t < 128) E2L[t] = P2[2 * t] + P2[2 * t + 1];
    __syncthreads();

    // ---- main MFMA loop ----
    const int lane = t & 63, wid = t >> 6;
    const int wr = wid >> 1, wc = wid & 1;        // 2x2 wave grid
    const int l15 = lane & 15, lk = lane >> 4;
    const int swz = (lane & 7) << 4;

    f32x4 acc[4][4];
    #pragma unroll
    for (int m = 0; m < 4; ++m)
        #pragma unroll
        for (int n = 0; n < 4; ++n)
            acc[m][n] = (f32x4){0.f, 0.f, 0.f, 0.f};

    int arow = bm * 128 + wr * 64 + l15;
    if (arow > B - 1) arow = B - 1;
    const char* ah = (const char*)qh + (size_t)arow * 256 + lk * 16;
    const char* al = (const char*)ql + (size_t)arow * 256 + lk * 16;
    const char* bh = EH + (wc * 64 + l15) * 256;
    const char* bl = EL + (wc * 64 + l15) * 256;

    #pragma unroll
    for (int kk = 0; kk < 4; ++kk) {
        short8 AH[4], AL[4], BH[4], BL[4];
        #pragma unroll
        for (int m = 0; m < 4; ++m) {
            AH[m] = *(const short8*)(ah + m * 4096 + kk * 64);
            AL[m] = *(const short8*)(al + m * 4096 + kk * 64);
        }
        const int ko = (kk * 64 + lk * 16) ^ swz;
        #pragma unroll
        for (int n = 0; n < 4; ++n) {
            BH[n] = *(const short8*)(bh + n * 4096 + ko);
            BL[n] = *(const short8*)(bl + n * 4096 + ko);
        }
        #pragma unroll
        for (int m = 0; m < 4; ++m)
            #pragma unroll
            for (int n = 0; n < 4; ++n)
                acc[m][n] = __builtin_amdgcn_mfma_f32_16x16x32_bf16(AH[m], BH[n], acc[m][n], 0, 0, 0);
        #pragma unroll
        for (int m = 0; m < 4; ++m)
            #pragma unroll
            for (int n = 0; n < 4; ++n)
                acc[m][n] = __builtin_amdgcn_mfma_f32_16x16x32_bf16(AH[m], BL[n], acc[m][n], 0, 0, 0);
        #pragma unroll
        for (int m = 0; m < 4; ++m)
            #pragma unroll
            for (int n = 0; n < 4; ++n)
                acc[m][n] = __builtin_amdgcn_mfma_f32_16x16x32_bf16(AL[m], BH[n], acc[m][n], 0, 0, 0);
    }

    // ---- fused epilogue + store ----
    const float c = C_CURV;
    #pragma unroll
    for (int n = 0; n < 4; ++n) {
        const int lcol = wc * 64 + n * 16 + l15;
        const int col  = bn * 128 + lcol;
        const bool cv  = (col < E);
        const float e2 = E2L[lcol];
        const float be = EBL[lcol];
        #pragma unroll
        for (int m = 0; m < 4; ++m) {
            #pragma unroll
            for (int r = 0; r < 4; ++r) {
                const int lrow = wr * 64 + m * 16 + lk * 4 + r;
                const int row  = bm * 128 + lrow;
                const float q2 = Q2L[lrow];
                const float bs = BSL[lrow];
                const float dot = acc[m][n][r];
                float T   = fmaf(-2.f * c, dot, 1.f);
                float A_  = fmaf(c, e2, T);
                float Bq  = fmaf(-c, q2, 1.f);
                float den = fmaf(c * c * q2, e2, T);
                den = fmaxf(den, EPSF);
                float inv = __builtin_amdgcn_rcpf(den);
                float num2 = fmaf(A_ * A_, q2, fmaf(Bq * Bq, e2, -2.f * A_ * Bq * dot));
                float sc = fmaf(-num2 * inv, inv, be + bs);
                if (cv && row < B)
                    __builtin_nontemporal_store(sc, out + (size_t)row * (size_t)E + col);
            }
        }
    }
}

extern "C" void kernel_launch(void* const* d_in, const int* in_sizes, int n_in,
                              void* d_out, int out_size, void* d_ws, size_t ws_size,
                              hipStream_t stream) {
    const float* ent       = (const float*)d_in[0];
    // d_in[1] = rel_embedding (unused)
    const int*   trip      = (const int*)d_in[2];
    const float* rel_diag  = (const float*)d_in[3];
    const float* rel_trans = (const float*)d_in[4];
    const float* ent_bias  = (const float*)d_in[5];

    const int D = 128;
    const int E = in_sizes[0] / D;
    const int B = in_sizes[2] / 3;

    unsigned char* ws = (unsigned char*)d_ws;
    unsigned short* qh  = (unsigned short*)ws;              // B*128 bf16
    unsigned short* qlo = (unsigned short*)(ws + 131072);   // B*128 bf16
    float* q2w = (float*)(ws + 262144);                     // B
    float* bsw = (float*)(ws + 262144 + 2048);              // B

    build_queries<<<B, 64, 0, stream>>>(ent, trip, rel_diag, rel_trans, ent_bias,
                                        qh, qlo, q2w, bsw);

    dim3 grid((E + 127) / 128, (B + 127) / 128);
    gemm_score<<<grid, 256, 68608, stream>>>(ent, ent_bias, qh, qlo, q2w, bsw,
                                             (float*)d_out, E, B);
}